// Round 1
// baseline (476.375 us; speedup 1.0000x reference)
//
#include <hip/hip_runtime.h>

#define B_ 128
#define N_ 576
#define K_ 16
#define D_ 768
#define NC_ 1000
#define TCPAD 772  // 768 + 4 pad, float4-aligned LDS rows

// ---------------------------------------------------------------------------
// Kernel A: scores = img . (text[cls] + fine[cls,k]),  Qexp = exp(scores/eps)
// written into the fine_label region of d_out (layout [b][n][k], f32).
// Grid: 4 blocks per b (144 rows each), 512 threads (8 waves).
// Each wave handles 3 rows per iteration, full-wave split over D.
// ---------------------------------------------------------------------------
__global__ __launch_bounds__(512, 4) void scores_exp_kernel(
    const float* __restrict__ img, const float* __restrict__ text,
    const float* __restrict__ fine, const int* __restrict__ target,
    float* __restrict__ fineL) {
  const int b = blockIdx.x >> 2;
  const int chunk = blockIdx.x & 3;
  const int tid = threadIdx.x;
  const int cls = target[b];

  __shared__ float tc[K_ * TCPAD];

  // stage text_c[k][d] = text[cls][d] + fine[cls][k][d]  (float4, coalesced)
  for (int i = tid; i < (K_ * D_ / 4); i += 512) {
    const int k = i / (D_ / 4);
    const int d4 = i % (D_ / 4);
    const float4 t = *(const float4*)&text[(size_t)cls * D_ + d4 * 4];
    const float4 f = *(const float4*)&fine[((size_t)cls * K_ + k) * D_ + d4 * 4];
    *(float4*)&tc[k * TCPAD + d4 * 4] =
        make_float4(t.x + f.x, t.y + f.y, t.z + f.z, t.w + f.w);
  }
  __syncthreads();

  const int wave = tid >> 6;
  const int lane = tid & 63;

  for (int g = 0; g < 6; ++g) {
    const int row0 = chunk * 144 + wave * 18 + g * 3;

    // load 3 rows of image: lane covers d = j*256 + lane*4 .. +3 (coalesced)
    float4 x[3][3];
#pragma unroll
    for (int r = 0; r < 3; ++r) {
      const float* ib = img + ((size_t)b * N_ + row0 + r) * D_ + (lane << 2);
#pragma unroll
      for (int j = 0; j < 3; ++j) x[r][j] = *(const float4*)&ib[j * 256];
    }

    float acc[3][16];
#pragma unroll
    for (int r = 0; r < 3; ++r)
#pragma unroll
      for (int k = 0; k < 16; ++k) acc[r][k] = 0.0f;

#pragma unroll
    for (int k = 0; k < 16; ++k) {
#pragma unroll
      for (int j = 0; j < 3; ++j) {
        const float4 t = *(const float4*)&tc[k * TCPAD + j * 256 + (lane << 2)];
#pragma unroll
        for (int r = 0; r < 3; ++r) {
          acc[r][k] += x[r][j].x * t.x;
          acc[r][k] += x[r][j].y * t.y;
          acc[r][k] += x[r][j].z * t.z;
          acc[r][k] += x[r][j].w * t.w;
        }
      }
    }

    // reduce each acc over all 64 lanes; apply exp(score/eps); lane 0 stores
#pragma unroll
    for (int r = 0; r < 3; ++r) {
#pragma unroll
      for (int k = 0; k < 16; ++k) {
        float v = acc[r][k];
        v += __shfl_xor(v, 1);
        v += __shfl_xor(v, 2);
        v += __shfl_xor(v, 4);
        v += __shfl_xor(v, 8);
        v += __shfl_xor(v, 16);
        v += __shfl_xor(v, 32);
        acc[r][k] = expf(v / 0.05f);  // uniform across lanes
      }
      if (lane == 0) {
        float4* dst = (float4*)&fineL[((size_t)b * N_ + row0 + r) * K_];
        dst[0] = make_float4(acc[r][0], acc[r][1], acc[r][2], acc[r][3]);
        dst[1] = make_float4(acc[r][4], acc[r][5], acc[r][6], acc[r][7]);
        dst[2] = make_float4(acc[r][8], acc[r][9], acc[r][10], acc[r][11]);
        dst[3] = make_float4(acc[r][12], acc[r][13], acc[r][14], acc[r][15]);
      }
    }
  }
}

// ---------------------------------------------------------------------------
// Kernel B: per-b Sinkhorn (3 iters) + argmax + outputs.
// One block per b, 576 threads (9 waves); thread n holds Q[:,n] (16 regs).
// Mirrors the reference normalization sequence with true f32 divisions.
// ---------------------------------------------------------------------------
__global__ __launch_bounds__(576) void sinkhorn_kernel(
    float* __restrict__ fineL, float* __restrict__ fineT,
    const int* __restrict__ target) {
  const int b = blockIdx.x;
  const int n = threadIdx.x;
  const int lane = n & 63;
  const int wave = n >> 6;

  __shared__ float red[9 * 16];

  float q[16];
  float4* rowp = (float4*)&fineL[((size_t)b * N_ + n) * K_];
  {
    const float4 a0 = rowp[0], a1 = rowp[1], a2 = rowp[2], a3 = rowp[3];
    q[0] = a0.x; q[1] = a0.y; q[2] = a0.z; q[3] = a0.w;
    q[4] = a1.x; q[5] = a1.y; q[6] = a1.z; q[7] = a1.w;
    q[8] = a2.x; q[9] = a2.y; q[10] = a2.z; q[11] = a2.w;
    q[12] = a3.x; q[13] = a3.y; q[14] = a3.z; q[15] = a3.w;
  }

  // global sum over (k, n) for this b
  float s = 0.0f;
#pragma unroll
  for (int k = 0; k < 16; ++k) s += q[k];
  s += __shfl_xor(s, 1);
  s += __shfl_xor(s, 2);
  s += __shfl_xor(s, 4);
  s += __shfl_xor(s, 8);
  s += __shfl_xor(s, 16);
  s += __shfl_xor(s, 32);
  if (lane == 0) red[wave] = s;
  __syncthreads();
  float S = 0.0f;
#pragma unroll
  for (int w = 0; w < 9; ++w) S += red[w];
#pragma unroll
  for (int k = 0; k < 16; ++k) q[k] = q[k] / S;

  for (int it = 0; it < 3; ++it) {
    __syncthreads();  // protect red before rewriting
    // row sums (over n) for each k
#pragma unroll
    for (int k = 0; k < 16; ++k) {
      float v = q[k];
      v += __shfl_xor(v, 1);
      v += __shfl_xor(v, 2);
      v += __shfl_xor(v, 4);
      v += __shfl_xor(v, 8);
      v += __shfl_xor(v, 16);
      v += __shfl_xor(v, 32);
      if (lane == 0) red[wave * 16 + k] = v;
    }
    __syncthreads();
#pragma unroll
    for (int k = 0; k < 16; ++k) {
      float r = 0.0f;
#pragma unroll
      for (int w = 0; w < 9; ++w) r += red[w * 16 + k];
      q[k] = q[k] / (r * 16.0f);
    }
    // column normalize (per-thread, no communication)
    float c = 0.0f;
#pragma unroll
    for (int k = 0; k < 16; ++k) c += q[k];
    const float cd = c * 576.0f;
#pragma unroll
    for (int k = 0; k < 16; ++k) q[k] = q[k] / cd;
  }

#pragma unroll
  for (int k = 0; k < 16; ++k) q[k] *= 576.0f;

  // argmax (strict >, first occurrence wins — matches jnp.argmax)
  int best = 0;
  float bv = q[0];
#pragma unroll
  for (int k = 1; k < 16; ++k)
    if (q[k] > bv) { bv = q[k]; best = k; }

  rowp[0] = make_float4(q[0], q[1], q[2], q[3]);
  rowp[1] = make_float4(q[4], q[5], q[6], q[7]);
  rowp[2] = make_float4(q[8], q[9], q[10], q[11]);
  rowp[3] = make_float4(q[12], q[13], q[14], q[15]);
  fineT[(size_t)b * N_ + n] = (float)(best * NC_ + target[b]);
}

extern "C" void kernel_launch(void* const* d_in, const int* in_sizes, int n_in,
                              void* d_out, int out_size, void* d_ws, size_t ws_size,
                              hipStream_t stream) {
  const float* img = (const float*)d_in[0];
  const float* text = (const float*)d_in[1];
  const float* fine = (const float*)d_in[2];
  const int* target = (const int*)d_in[3];

  float* fineL = (float*)d_out;                          // [B][N][K] f32
  float* fineT = (float*)d_out + (size_t)B_ * N_ * K_;   // [B*N] as f32

  scores_exp_kernel<<<B_ * 4, 512, 0, stream>>>(img, text, fine, target, fineL);
  sinkhorn_kernel<<<B_, 576, 0, stream>>>(fineL, fineT, target);
}

// Round 3
// 262.916 us; speedup vs baseline: 1.8119x; 1.8119x over previous
//
#include <hip/hip_runtime.h>

#define B_ 128
#define N_ 576
#define K_ 16
#define D_ 768
#define NC_ 1000
#define TCPAD 772  // 768 + 4 pad, float4-aligned LDS rows

// ---------------------------------------------------------------------------
// Kernel A: scores = img . (text[cls] + fine[cls,k]),  Qexp = exp(scores/eps)
// written into the fine_label region of d_out (layout [b][n][k], f32).
// Grid: 4 blocks per b (144 rows each), 512 threads (8 waves).
// Each wave: 2 rows per iteration, full-wave split over D, j-outer loop so
// only 2 x-fragments are live (low VGPR, no spills).
//
// Cross-lane reduction: reduce-scatter with step order xor1,2,4,8 (split on
// k-bit 0..3, keep k's whose bit matches lane's bit, local+received) then
// xor16, xor32 full-reduce. This is BIT-IDENTICAL to the round-1 full
// butterfly (xor1..32, v = v_local + v_remote) by commutativity induction —
// do not change the order: argmax ties amplify any rounding difference.
// Lane L ends holding total[k = L & 15].
// ---------------------------------------------------------------------------
__global__ __launch_bounds__(512, 8) void scores_exp_kernel(
    const float* __restrict__ img, const float* __restrict__ text,
    const float* __restrict__ fine, const int* __restrict__ target,
    float* __restrict__ fineL) {
  const int b = blockIdx.x >> 2;
  const int chunk = blockIdx.x & 3;
  const int tid = threadIdx.x;
  const int cls = target[b];

  __shared__ float tc[K_ * TCPAD];

  // stage text_c[k][d] = text[cls][d] + fine[cls][k][d]  (float4, coalesced)
  for (int i = tid; i < (K_ * D_ / 4); i += 512) {
    const int k = i / (D_ / 4);
    const int d4 = i % (D_ / 4);
    const float4 t = *(const float4*)&text[(size_t)cls * D_ + d4 * 4];
    const float4 f = *(const float4*)&fine[((size_t)cls * K_ + k) * D_ + d4 * 4];
    *(float4*)&tc[k * TCPAD + d4 * 4] =
        make_float4(t.x + f.x, t.y + f.y, t.z + f.z, t.w + f.w);
  }
  __syncthreads();

  const int wave = tid >> 6;
  const int lane = tid & 63;
  const int c0 = lane & 1;
  const int c1 = (lane >> 1) & 1;
  const int c2 = (lane >> 2) & 1;
  const int c3 = (lane >> 3) & 1;

  // reduce-scatter, bit-identical to full xor1..32 butterfly (see above)
  auto reduce16 = [&](const float* a) -> float {
    float a8[8];
#pragma unroll
    for (int i = 0; i < 8; ++i) {
      const float kept = a[2 * i + c0];
      const float sent = a[2 * i + (c0 ^ 1)];
      a8[i] = kept + __shfl_xor(sent, 1);
    }
    float a4v[4];
#pragma unroll
    for (int i = 0; i < 4; ++i) {
      const float kept = a8[2 * i + c1];
      const float sent = a8[2 * i + (c1 ^ 1)];
      a4v[i] = kept + __shfl_xor(sent, 2);
    }
    float a2v[2];
#pragma unroll
    for (int i = 0; i < 2; ++i) {
      const float kept = a4v[2 * i + c2];
      const float sent = a4v[2 * i + (c2 ^ 1)];
      a2v[i] = kept + __shfl_xor(sent, 4);
    }
    const float kept = a2v[c3];
    const float sent = a2v[c3 ^ 1];
    float v = kept + __shfl_xor(sent, 8);
    v += __shfl_xor(v, 16);
    v += __shfl_xor(v, 32);
    return v;  // lane L holds total[k = L & 15]
  };

  for (int g = 0; g < 9; ++g) {
    const int row0 = chunk * 144 + wave * 18 + g * 2;

    float acc0[16], acc1[16];
#pragma unroll
    for (int k = 0; k < 16; ++k) { acc0[k] = 0.0f; acc1[k] = 0.0f; }

    const float* ib0 = img + ((size_t)b * N_ + row0) * D_ + (lane << 2);
    const float* ib1 = ib0 + D_;

#pragma unroll
    for (int j = 0; j < 3; ++j) {
      const float4 x0 = *(const float4*)&ib0[j * 256];
      const float4 x1 = *(const float4*)&ib1[j * 256];
#pragma unroll
      for (int k = 0; k < 16; ++k) {
        const float4 t = *(const float4*)&tc[k * TCPAD + j * 256 + (lane << 2)];
        acc0[k] += x0.x * t.x;
        acc0[k] += x0.y * t.y;
        acc0[k] += x0.z * t.z;
        acc0[k] += x0.w * t.w;
        acc1[k] += x1.x * t.x;
        acc1[k] += x1.y * t.y;
        acc1[k] += x1.z * t.z;
        acc1[k] += x1.w * t.w;
      }
    }

    const float v0 = reduce16(acc0);
    const float v1 = reduce16(acc1);
    if (lane < 16) {
      fineL[((size_t)b * N_ + row0) * K_ + lane] = expf(v0 / 0.05f);
      fineL[((size_t)b * N_ + row0 + 1) * K_ + lane] = expf(v1 / 0.05f);
    }
  }
}

// ---------------------------------------------------------------------------
// Kernel B: per-b Sinkhorn (3 iters) + argmax + outputs.
// One block per b, 576 threads (9 waves); thread n holds Q[:,n] (16 regs).
// Mirrors the reference normalization sequence with true f32 divisions.
// ---------------------------------------------------------------------------
__global__ __launch_bounds__(576) void sinkhorn_kernel(
    float* __restrict__ fineL, float* __restrict__ fineT,
    const int* __restrict__ target) {
  const int b = blockIdx.x;
  const int n = threadIdx.x;
  const int lane = n & 63;
  const int wave = n >> 6;

  __shared__ float red[9 * 16];

  float q[16];
  float4* rowp = (float4*)&fineL[((size_t)b * N_ + n) * K_];
  {
    const float4 a0 = rowp[0], a1 = rowp[1], a2 = rowp[2], a3 = rowp[3];
    q[0] = a0.x; q[1] = a0.y; q[2] = a0.z; q[3] = a0.w;
    q[4] = a1.x; q[5] = a1.y; q[6] = a1.z; q[7] = a1.w;
    q[8] = a2.x; q[9] = a2.y; q[10] = a2.z; q[11] = a2.w;
    q[12] = a3.x; q[13] = a3.y; q[14] = a3.z; q[15] = a3.w;
  }

  // global sum over (k, n) for this b
  float s = 0.0f;
#pragma unroll
  for (int k = 0; k < 16; ++k) s += q[k];
  s += __shfl_xor(s, 1);
  s += __shfl_xor(s, 2);
  s += __shfl_xor(s, 4);
  s += __shfl_xor(s, 8);
  s += __shfl_xor(s, 16);
  s += __shfl_xor(s, 32);
  if (lane == 0) red[wave] = s;
  __syncthreads();
  float S = 0.0f;
#pragma unroll
  for (int w = 0; w < 9; ++w) S += red[w];
#pragma unroll
  for (int k = 0; k < 16; ++k) q[k] = q[k] / S;

  for (int it = 0; it < 3; ++it) {
    __syncthreads();  // protect red before rewriting
    // row sums (over n) for each k
#pragma unroll
    for (int k = 0; k < 16; ++k) {
      float v = q[k];
      v += __shfl_xor(v, 1);
      v += __shfl_xor(v, 2);
      v += __shfl_xor(v, 4);
      v += __shfl_xor(v, 8);
      v += __shfl_xor(v, 16);
      v += __shfl_xor(v, 32);
      if (lane == 0) red[wave * 16 + k] = v;
    }
    __syncthreads();
#pragma unroll
    for (int k = 0; k < 16; ++k) {
      float r = 0.0f;
#pragma unroll
      for (int w = 0; w < 9; ++w) r += red[w * 16 + k];
      q[k] = q[k] / (r * 16.0f);
    }
    // column normalize (per-thread, no communication)
    float c = 0.0f;
#pragma unroll
    for (int k = 0; k < 16; ++k) c += q[k];
    const float cd = c * 576.0f;
#pragma unroll
    for (int k = 0; k < 16; ++k) q[k] = q[k] / cd;
  }

#pragma unroll
  for (int k = 0; k < 16; ++k) q[k] *= 576.0f;

  // argmax (strict >, first occurrence wins — matches jnp.argmax)
  int best = 0;
  float bv = q[0];
#pragma unroll
  for (int k = 1; k < 16; ++k)
    if (q[k] > bv) { bv = q[k]; best = k; }

  rowp[0] = make_float4(q[0], q[1], q[2], q[3]);
  rowp[1] = make_float4(q[4], q[5], q[6], q[7]);
  rowp[2] = make_float4(q[8], q[9], q[10], q[11]);
  rowp[3] = make_float4(q[12], q[13], q[14], q[15]);
  fineT[(size_t)b * N_ + n] = (float)(best * NC_ + target[b]);
}

extern "C" void kernel_launch(void* const* d_in, const int* in_sizes, int n_in,
                              void* d_out, int out_size, void* d_ws, size_t ws_size,
                              hipStream_t stream) {
  const float* img = (const float*)d_in[0];
  const float* text = (const float*)d_in[1];
  const float* fine = (const float*)d_in[2];
  const int* target = (const int*)d_in[3];

  float* fineL = (float*)d_out;                          // [B][N][K] f32
  float* fineT = (float*)d_out + (size_t)B_ * N_ * K_;   // [B*N] as f32

  scores_exp_kernel<<<B_ * 4, 512, 0, stream>>>(img, text, fine, target, fineL);
  sinkhorn_kernel<<<B_, 576, 0, stream>>>(fineL, fineT, target);
}